// Round 7
// baseline (597.483 us; speedup 1.0000x reference)
//
#include <hip/hip_runtime.h>

#define DEV __device__ __forceinline__

// ---------- cross-lane helpers (all VALU, no LDS) ----------

template <int CTRL>
DEV float dppf(float x) {
  return __int_as_float(__builtin_amdgcn_update_dpp(
      0, __float_as_int(x), CTRL, 0xF, 0xF, true));
}

// Butterfly sum within each 32-lane half; result broadcast to all lanes of the half.
DEV float wsum32(float v) {
  v += dppf<0xB1>(v);   // xor1
  v += dppf<0x4E>(v);   // xor2
  v += dppf<0x141>(v);  // xor4 (row_half_mirror)
  v += dppf<0x140>(v);  // xor8 (row_mirror)
#if __has_builtin(__builtin_amdgcn_permlane16_swap)
  {
    auto p = __builtin_amdgcn_permlane16_swap(
        __float_as_uint(v), __float_as_uint(v), false, false);
    v = __uint_as_float(p[0]) + __uint_as_float(p[1]);  // v[l] + v[l^16]
  }
#else
  v += __shfl_xor(v, 16, 64);
#endif
  return v;
}

// v[l] + v[l^32] (combine the two half-row partial dots).
DEV float halfsum(float v) {
#if __has_builtin(__builtin_amdgcn_permlane32_swap)
  auto p = __builtin_amdgcn_permlane32_swap(
      __float_as_uint(v), __float_as_uint(v), false, false);
  return __uint_as_float(p[0]) + __uint_as_float(p[1]);
#else
  return v + __shfl_xor(v, 32, 64);
#endif
}

#define SLEN 1024
#define NH 8
#define DH 32
#define HSTRIDE 2048  // floats per timestep (B*NH*DH)

// ---------- phase 1: x = softmax32(h), staged into d_out ----------

__global__ __launch_bounds__(256)
void srwm_xsm(const float* __restrict__ h, float* __restrict__ x) {
  int i = blockIdx.x * 256 + threadIdx.x;
  float e = __expf(h[i]);
  x[i] = __fdividef(e, wsum32(e));  // 32-groups align with lane halves
}

// ---------- phase 2: the scan. One block (4 waves) per (b,h). ----------
// Wave w owns one matrix: 0:Wy 1:Wq 2:Wk 3:wb^T. Lane (r=lane&31, c0) holds
// cols c0..c0+15 of row r (w<3) or wb^T chunk wb[c0+j][r&3] (w==3).
//
// Deferred-update recurrence (identical math to R6):
// entering region T: regs hold q_{T-1},k_{T-1} chunks (QV,KV), B_{T-1}[w] (BW);
// W = W_{T-1}; preA = W_{T-1} x_T.
//
// KEY FIX vs R6: 4-deep x prefetch pipeline. R6 prefetched x_{T+2} in region T
// and consumed it in region T+1's preA -> 1-region budget < global-load
// latency -> every region tail stalled on vmcnt. Now region T prefetches
// x_{T+4} into the buffer vacated by its s-dot (x_T); first use is region
// T+3's preA = 3-region budget, covering HBM-miss latency. Pure register
// renaming (loop unrolled x4, static rotation X0..X3).

#define BARRIER()                                        \
  do {                                                   \
    __builtin_amdgcn_sched_barrier(0);                   \
    asm volatile("s_waitcnt lgkmcnt(0)");                \
    __builtin_amdgcn_sched_barrier(0);                   \
    __builtin_amdgcn_s_barrier();                        \
    __builtin_amdgcn_sched_barrier(0);                   \
  } while (0)

#define REGION(T, P, QV, KV, BW, QN, KN, BN, XS, XP)                          \
  {                                                                           \
    /* ---- on-path: dv, d-matvec + s-dot (interleaved), u, a_T ---- */       \
    float dv[16];                                                             \
    _Pragma("unroll") for (int j = 0; j < 16; ++j) dv[j] = QV[j] - KV[j];     \
    float d0 = 0.f, d1 = 0.f, d2 = 0.f, d3 = 0.f, s0 = 0.f, s1 = 0.f;         \
    _Pragma("unroll") for (int j = 0; j < 16; j += 4) {                       \
      d0 = fmaf(W[j],     dv[j],     d0);                                     \
      d1 = fmaf(W[j + 1], dv[j + 1], d1);                                     \
      d2 = fmaf(W[j + 2], dv[j + 2], d2);                                     \
      d3 = fmaf(W[j + 3], dv[j + 3], d3);                                     \
      s0 = fmaf(KV[j],     XS[j],     s0);                                    \
      s1 = fmaf(KV[j + 1], XS[j + 1], s1);                                    \
      s0 = fmaf(KV[j + 2], XS[j + 2], s0);                                    \
      s1 = fmaf(KV[j + 3], XS[j + 3], s1);                                    \
    }                                                                         \
    float dsum = halfsum((d0 + d1) + (d2 + d3));                              \
    float sv   = halfsum(s0 + s1);                                            \
    float u  = BW * dsum;                                                     \
    float aA = fmaf(u, sv, preA);                                             \
    if (w == 0) {                                                             \
      if (lane < DH) xb[(size_t)(T) * HSTRIDE + lane] = aA;  /* y_T */        \
    } else if (w == 1) {                                                      \
      float e = __expf(aA); qs[P][r] = __fdividef(e, wsum32(e));              \
    } else if (w == 2) {                                                      \
      float e = __expf(aA); ks2[P][r] = __fdividef(e, wsum32(e));             \
    } else {                                                                  \
      float sg = __fdividef(1.f, 1.f + __expf(-aA));                          \
      if (lane < 4) bss[P][lane] = sg;                                        \
    }                                                                         \
    BARRIER();                                                                \
    /* ---- post-barrier: reads first (latency), reg-work under them ---- */  \
    _Pragma("unroll") for (int j = 0; j < 16; j += 4) {                       \
      *(float4*)&QN[j] = *(const float4*)&qs[P][c0 + j];                      \
      *(float4*)&KN[j] = *(const float4*)&ks2[P][c0 + j];                     \
    }                                                                         \
    BN = bss[P][w];                                                           \
    /* W <- W_T (uses OLD k = KV) */                                          \
    _Pragma("unroll") for (int j = 0; j < 16; ++j)                            \
      W[j] = fmaf(u, KV[j], W[j]);                                            \
    /* prefetch x_{T+4} into XS (x_T dead after s-dot; 3-region budget) */    \
    int t4 = (T) + 4; if (t4 > SLEN - 1) t4 = SLEN - 1;                       \
    _Pragma("unroll") for (int j = 0; j < 16; j += 4)                         \
      *(float4*)&XS[j] = *(const float4*)(xb + (size_t)t4 * HSTRIDE + c0 + j);\
    /* preA = W_T x_{T+1} */                                                  \
    float p0 = 0.f, p1 = 0.f, p2 = 0.f, p3 = 0.f;                             \
    _Pragma("unroll") for (int j = 0; j < 16; j += 4) {                       \
      p0 = fmaf(W[j],     XP[j],     p0);                                     \
      p1 = fmaf(W[j + 1], XP[j + 1], p1);                                     \
      p2 = fmaf(W[j + 2], XP[j + 2], p2);                                     \
      p3 = fmaf(W[j + 3], XP[j + 3], p3);                                     \
    }                                                                         \
    preA = halfsum((p0 + p1) + (p2 + p3));                                    \
  }

__global__ __launch_bounds__(256, 1)
void srwm_scan(const float* __restrict__ Wy0, const float* __restrict__ Wq0,
               const float* __restrict__ Wk0, const float* __restrict__ wb0,
               float* xy) {
  __shared__ float qs[2][DH];
  __shared__ float ks2[2][DH];
  __shared__ float bss[2][4];

  const int bh   = blockIdx.x;        // 0..63
  const int hd   = bh & 7;
  const int w    = threadIdx.x >> 6;  // wave: 0..3
  const int lane = threadIdx.x & 63;
  const int r    = lane & 31;
  const int c0   = (lane >> 5) * 16;

  // ---- load this wave's matrix ----
  float W[16];
  if (w < 3) {
    const float* src = (w == 0) ? Wy0 : (w == 1) ? Wq0 : Wk0;
    const float* p = src + (hd * DH + r) * DH + c0;
#pragma unroll
    for (int j = 0; j < 16; j += 4) *(float4*)&W[j] = *(const float4*)(p + j);
  } else {
    const int kk = r & 3;
#pragma unroll
    for (int j = 0; j < 16; ++j) W[j] = wb0[(hd * DH + c0 + j) * 4 + kk];
  }

  float* xb = xy + bh * DH;  // x/y for this (b,h): element [t*HSTRIDE + j]

  // ---- prologue: X0..X3 <- x_0..x_3; q_{-1}=k_{-1}=0, B_{-1}=0 in regs;
  //      preA = W_0 x_0 (u_{-1}=0 so W_{-1} == W_0) ----
  float X0[16], X1[16], X2[16], X3[16];
#pragma unroll
  for (int j = 0; j < 16; j += 4) {
    *(float4*)&X0[j] = *(const float4*)(xb + c0 + j);
    *(float4*)&X1[j] = *(const float4*)(xb + (size_t)1 * HSTRIDE + c0 + j);
    *(float4*)&X2[j] = *(const float4*)(xb + (size_t)2 * HSTRIDE + c0 + j);
    *(float4*)&X3[j] = *(const float4*)(xb + (size_t)3 * HSTRIDE + c0 + j);
  }
  float p0 = 0.f, p1 = 0.f, p2 = 0.f, p3 = 0.f;
#pragma unroll
  for (int j = 0; j < 16; j += 4) {
    p0 = fmaf(W[j],     X0[j],     p0);
    p1 = fmaf(W[j + 1], X0[j + 1], p1);
    p2 = fmaf(W[j + 2], X0[j + 2], p2);
    p3 = fmaf(W[j + 3], X0[j + 3], p3);
  }
  float preA = halfsum((p0 + p1) + (p2 + p3));

  float QA[16], KA[16], QB[16], KB[16];
#pragma unroll
  for (int j = 0; j < 16; ++j) { QA[j] = 0.f; KA[j] = 0.f; }
  float BwA = 0.f, BwB = 0.f;

  __syncthreads();

  for (int t = 0; t < SLEN; t += 4) {
    REGION(t,     0, QA, KA, BwA, QB, KB, BwB, X0, X1);
    REGION(t + 1, 1, QB, KB, BwB, QA, KA, BwA, X1, X2);
    REGION(t + 2, 0, QA, KA, BwA, QB, KB, BwB, X2, X3);
    REGION(t + 3, 1, QB, KB, BwB, QA, KA, BwA, X3, X0);
  }
}

// ---------- phase 3: out = h + ys @ Wout^T  (in-place over ys==out) ----------

__global__ __launch_bounds__(256)
void srwm_proj(const float* __restrict__ h, const float* __restrict__ ys,
               const float* __restrict__ Wout, float* __restrict__ out) {
  __shared__ float ytile[32][256];  // 32 KB
  const int r0  = blockIdx.x * 32;
  const int tid = threadIdx.x;

  const float4* src = (const float4*)(ys + (size_t)r0 * 256);
  float4*       dst = (float4*)(&ytile[0][0]);
#pragma unroll
  for (int i = 0; i < 8; ++i) dst[tid + i * 256] = src[tid + i * 256];
  __syncthreads();

  float acc[32];
#pragma unroll
  for (int m = 0; m < 32; ++m) acc[m] = 0.f;

  const float* wrow = Wout + (size_t)tid * 256;
  for (int k = 0; k < 256; k += 4) {
    float4 w = *(const float4*)(wrow + k);
#pragma unroll
    for (int m = 0; m < 32; ++m) {
      float4 y4 = *(const float4*)(&ytile[m][k]);
      acc[m] = fmaf(w.x, y4.x,
               fmaf(w.y, y4.y,
               fmaf(w.z, y4.z,
               fmaf(w.w, y4.w, acc[m]))));
    }
  }

#pragma unroll
  for (int m = 0; m < 32; ++m) {
    int row = r0 + m;
    out[(size_t)row * 256 + tid] = h[(size_t)row * 256 + tid] + acc[m];
  }
}

// ---------- launcher ----------

extern "C" void kernel_launch(void* const* d_in, const int* in_sizes, int n_in,
                              void* d_out, int out_size, void* d_ws, size_t ws_size,
                              hipStream_t stream) {
  const float* h    = (const float*)d_in[0];
  const float* Wy0  = (const float*)d_in[1];
  const float* Wq0  = (const float*)d_in[2];
  const float* Wk0  = (const float*)d_in[3];
  const float* wb0  = (const float*)d_in[4];
  const float* Wout = (const float*)d_in[5];
  float* out = (float*)d_out;

  // d_out triple duty: x (phase1) -> progressively overwritten by y (phase2)
  // -> final output (phase3, in-place via LDS tile).
  srwm_xsm <<<SLEN * HSTRIDE / 256, 256, 0, stream>>>(h, out);
  srwm_scan<<<64, 256, 0, stream>>>(Wy0, Wq0, Wk0, wb0, out);
  srwm_proj<<<256, 256, 0, stream>>>(h, out, Wout, out);
}